// Round 11
// baseline (229.156 us; speedup 1.0000x reference)
//
#include <hip/hip_runtime.h>
#include <hip/hip_bf16.h>

// x [4,2048,1024] fp32; Wq/Wk/Wv [1024,1024] fp32. Causal attention.
// Algebra: scores = x Wq Wk^T x^T = T x^T with T = x M'^T, M' = Wk Wq^T.
//
// LDS swizzle (round 10, proven: conflicts 4.19M -> 0): data for k-quad q of
// row r sits at qslot = q ^ ((r>>1)&3); applied on the GLOBAL source column
// (global_load_lds writes linearly), reads XOR the same term.
// This round: tv_gemm's iter split into 2 fine phases (m201 template):
// {ds_read half-tile; barrier; setprio1; 16 MFMA; setprio0; barrier} x2,
// on the unchanged 3-slot / vmcnt(12) / zero-drain skeleton.
#define NB 4
#define SB 2048
#define DD 1024
#define BM 128
#define BN 128
#define BK 32

typedef __attribute__((ext_vector_type(8))) short bf16x8;
typedef __attribute__((ext_vector_type(4))) short bf16x4;
typedef __attribute__((ext_vector_type(4))) float f32x4;
typedef unsigned int u32;

__device__ __forceinline__ float bf2f(unsigned short u) {
    return __uint_as_float(((u32)u) << 16);
}
__device__ __forceinline__ short f2bf(float f) {
    u32 u = __float_as_uint(f);
    u32 r = (u + 0x7fffu + ((u >> 16) & 1u)) >> 16;
    return (short)r;
}

// Counted waits + raw barrier: prefetched tiles stay in flight across
// barriers; no full drain in steady state.
__device__ __forceinline__ void wait_vm12() {
    asm volatile("s_waitcnt vmcnt(12)" ::: "memory");
}
__device__ __forceinline__ void wait_vm6() {
    asm volatile("s_waitcnt vmcnt(6)" ::: "memory");
}
__device__ __forceinline__ void wait_vm0() {
    asm volatile("s_waitcnt vmcnt(0)" ::: "memory");
}
__device__ __forceinline__ void barrier_raw() {
    __builtin_amdgcn_s_barrier();
    asm volatile("" ::: "memory");   // no LDS access motion across barrier
}

// ---------------------------------------------------------------------------
// UNSWIZZLED MFMA tile step (prep_mm only — matches stage_f32_128x32 writes).
// ---------------------------------------------------------------------------
__device__ __forceinline__ void mfma_step(const short* As, const short* Bs,
                                          f32x4 (&acc)[4][4], int lane, int wave)
{
    const int wm = (wave >> 1) * 64, wn = (wave & 1) * 64;
    const int fr = lane & 15;
    const int quad = lane >> 4;
    bf16x8 af[4], bf[4];
#pragma unroll
    for (int t = 0; t < 4; t++) {
        af[t] = *(const bf16x8*)&As[(wm + t * 16 + fr) * BK + quad * 8];
        bf[t] = *(const bf16x8*)&Bs[(wn + t * 16 + fr) * BK + quad * 8];
    }
#pragma unroll
    for (int mt = 0; mt < 4; mt++)
#pragma unroll
        for (int nt = 0; nt < 4; nt++)
            acc[mt][nt] = __builtin_amdgcn_mfma_f32_16x16x32_bf16(
                af[mt], bf[nt], acc[mt][nt], 0, 0, 0);
}

// 128 x BN=64 swizzled tile step: wave owns 32-row m-slice, full 64-col n.
__device__ __forceinline__ void mfma_step_pv_swz(const short* As,
                                                 const short* Bs,
                                                 f32x4 (&acc)[2][4], int lane,
                                                 int wave)
{
    const int wm = wave * 32;
    const int fr = lane & 15;
    const int qa = (lane >> 4) ^ ((fr >> 1) & 3);
    bf16x8 af[2], bf[4];
#pragma unroll
    for (int t = 0; t < 2; t++)
        af[t] = *(const bf16x8*)&As[(wm + t * 16 + fr) * BK + qa * 8];
#pragma unroll
    for (int t = 0; t < 4; t++)
        bf[t] = *(const bf16x8*)&Bs[(t * 16 + fr) * BK + qa * 8];
#pragma unroll
    for (int mt = 0; mt < 2; mt++)
#pragma unroll
        for (int nt = 0; nt < 4; nt++)
            acc[mt][nt] = __builtin_amdgcn_mfma_f32_16x16x32_bf16(
                af[mt], bf[nt], acc[mt][nt], 0, 0, 0);
}

// bf16 staging, SWIZZLED SOURCE: LDS dest linear; lane fetches global k-quad
// (lane&3)^((lane>>3)&3) so LDS slot (row,qslot) holds quad qslot^((row>>1)&3).
__device__ __forceinline__ void stage128x32(const short* __restrict__ g, int ld,
                                            short* lds, int tid) {
    const int wave = tid >> 6, lane = tid & 63;
    const int r = lane >> 2;
    const int c = ((lane & 3) ^ ((lane >> 3) & 3)) * 8;
#pragma unroll
    for (int i = 0; i < 2; i++) {
        const int chunk = wave * 2 + i;
        const short* gp = g + (size_t)(chunk * 16 + r) * ld + c;
        __builtin_amdgcn_global_load_lds(
            (const __attribute__((address_space(1))) u32*)gp,
            (__attribute__((address_space(3))) u32*)(lds + chunk * 512 + lane * 8),
            16, 0, 0);
    }
}

// 64x32 tile, swizzled source: one 16B global_load_lds per thread.
__device__ __forceinline__ void stage64x32(const short* __restrict__ g, int ld,
                                           short* lds, int tid) {
    const int wave = tid >> 6, lane = tid & 63;
    const int r = lane >> 2;
    const int c = ((lane & 3) ^ ((lane >> 3) & 3)) * 8;
    const short* gp = g + (size_t)(wave * 16 + r) * ld + c;
    __builtin_amdgcn_global_load_lds(
        (const __attribute__((address_space(1))) u32*)gp,
        (__attribute__((address_space(3))) u32*)(lds + wave * 512 + lane * 8),
        16, 0, 0);
}

// ---------------------------------------------------------------------------
// Stage one K64 tile (A 256x64 + B 128x64) into a 48KB slot as [2ks][rows][32]
// sub-tiles, swizzled source. A: [0,16384) = [ks][256][32]; B at +16384:
// [ks][128][32]. 6 loads/thread (512 thr).
// ---------------------------------------------------------------------------
__device__ __forceinline__ void stage_tile256(const short* __restrict__ gA,
                                              int lda,
                                              const short* __restrict__ gB,
                                              int ldb, short* slot, int tid) {
    const int w = tid >> 6, l = tid & 63;
    const int lr = l >> 2;           // lane row within a 16-row group
    const int lc = ((l & 3) ^ ((l >> 3) & 3)) * 8;  // swizzled k-quad
#pragma unroll
    for (int i = 0; i < 4; i++) {    // A rounds: dest shorts i*4096 + w*512
        const int ks = i >> 1;
        const int row = (i & 1) * 128 + w * 16 + lr;
        const short* gp = gA + (size_t)row * lda + ks * 32 + lc;
        __builtin_amdgcn_global_load_lds(
            (const __attribute__((address_space(1))) u32*)gp,
            (__attribute__((address_space(3))) u32*)(slot + i * 4096 + w * 512 + l * 8),
            16, 0, 0);
    }
    short* bbase = slot + 16384;
#pragma unroll
    for (int i = 0; i < 2; i++) {    // B: [ks=i][128][32]
        const int row = w * 16 + lr;
        const short* gp = gB + (size_t)row * ldb + i * 32 + lc;
        __builtin_amdgcn_global_load_lds(
            (const __attribute__((address_space(1))) u32*)gp,
            (__attribute__((address_space(3))) u32*)(bbase + i * 4096 + w * 512 + l * 8),
            16, 0, 0);
    }
}

// fp32 source staging: load fp32, convert, ds_write (prep_mm only; unswizzled,
// matched with the unswizzled mfma_step).
__device__ __forceinline__ void stage_f32_128x32(const float* __restrict__ g,
                                                 int ld, short* lds, int tid) {
    const int r = tid >> 1;
    const int c = (tid & 1) * 16;
    const float* gp = &g[(size_t)r * ld + c];
    float4 v0 = *(const float4*)(gp + 0);
    float4 v1 = *(const float4*)(gp + 4);
    float4 v2 = *(const float4*)(gp + 8);
    float4 v3 = *(const float4*)(gp + 12);
    bf16x8 o0, o1;
    o0[0] = f2bf(v0.x); o0[1] = f2bf(v0.y); o0[2] = f2bf(v0.z); o0[3] = f2bf(v0.w);
    o0[4] = f2bf(v1.x); o0[5] = f2bf(v1.y); o0[6] = f2bf(v1.z); o0[7] = f2bf(v1.w);
    o1[0] = f2bf(v2.x); o1[1] = f2bf(v2.y); o1[2] = f2bf(v2.z); o1[3] = f2bf(v2.w);
    o1[4] = f2bf(v3.x); o1[5] = f2bf(v3.y); o1[6] = f2bf(v3.z); o1[7] = f2bf(v3.w);
    *(bf16x8*)&lds[r * BK + c] = o0;
    *(bf16x8*)&lds[r * BK + c + 8] = o1;
}

// ---------------------------------------------------------------------------
// Fused prep + split-k mm:
//   bx in [0,256):       M' partials: chunk c=bx>>6 computes
//                        Mp4[c][m][n] = sum_{k in c*256..+256} Wk[m][k]Wq[n][k]
//   bx in [256,4352):    cast x fp32->bf16 (8 elem/thr)
//   bx in [4352,4608):   cast+transpose Wv -> Wvt[n][k]
// ---------------------------------------------------------------------------
__global__ __launch_bounds__(256) void prep_mm(
    const float* __restrict__ x, const float* __restrict__ Wq,
    const float* __restrict__ Wk, const float* __restrict__ Wv,
    short* __restrict__ xb, short* __restrict__ Wvt, float* __restrict__ Mp4)
{
    __shared__ short As[BM * BK], Bs[BN * BK];
    __shared__ short t[64][65];
    const int bx = blockIdx.x;
    const int tid = threadIdx.x;
    if (bx < 256) {
        const int ch = bx >> 6;            // split-k chunk, 256 wide
        const int t64 = bx & 63;
        const int m0 = (t64 >> 3) * BM;
        const int n0 = (t64 & 7) * BN;
        const int kbase = ch * 256;
        const int lane = tid & 63, wave = tid >> 6;
        f32x4 acc[4][4];
#pragma unroll
        for (int a = 0; a < 4; a++)
#pragma unroll
            for (int b = 0; b < 4; b++) acc[a][b] = (f32x4){0.f, 0.f, 0.f, 0.f};
        for (int k0 = 0; k0 < 256; k0 += BK) {
            stage_f32_128x32(Wk + (size_t)m0 * DD + kbase + k0, DD, As, tid);
            stage_f32_128x32(Wq + (size_t)n0 * DD + kbase + k0, DD, Bs, tid);
            __syncthreads();
            mfma_step(As, Bs, acc, lane, wave);
            __syncthreads();
        }
        const int wm = (wave >> 1) * 64, wn = (wave & 1) * 64;
        const int fr = lane & 15, quad = lane >> 4;
        float* Mc = Mp4 + (size_t)ch * DD * DD;
#pragma unroll
        for (int mt = 0; mt < 4; mt++)
#pragma unroll
            for (int nt = 0; nt < 4; nt++)
#pragma unroll
                for (int r = 0; r < 4; r++) {
                    const size_t m = m0 + wm + mt * 16 + quad * 4 + r;
                    const size_t n = n0 + wn + nt * 16 + fr;
                    Mc[m * DD + n] = acc[mt][nt][r];
                }
        return;
    }
    if (bx < 4352) {
        const size_t i = ((size_t)(bx - 256) * 256 + tid) * 8;
        float4 a = *(const float4*)&x[i];
        float4 b = *(const float4*)&x[i + 4];
        bf16x8 o;
        o[0] = f2bf(a.x); o[1] = f2bf(a.y); o[2] = f2bf(a.z); o[3] = f2bf(a.w);
        o[4] = f2bf(b.x); o[5] = f2bf(b.y); o[6] = f2bf(b.z); o[7] = f2bf(b.w);
        *(bf16x8*)&xb[i] = o;
        return;
    }
    const int rr = bx - 4352;
    const int k0 = (rr & 15) * 64;
    const int n0 = (rr >> 4) * 64;
    {
        const int r = tid >> 4;
        const int c = (tid & 15) * 4;
#pragma unroll
        for (int i = 0; i < 4; i++) {
            float4 v = *(const float4*)&Wv[(size_t)(k0 + i * 16 + r) * DD + n0 + c];
            t[i * 16 + r][c + 0] = f2bf(v.x);
            t[i * 16 + r][c + 1] = f2bf(v.y);
            t[i * 16 + r][c + 2] = f2bf(v.z);
            t[i * 16 + r][c + 3] = f2bf(v.w);
        }
    }
    __syncthreads();
    {
        const int r = tid >> 3;
        const int c = (tid & 7) * 8;
#pragma unroll
        for (int i = 0; i < 2; i++) {
            bf16x8 o;
#pragma unroll
            for (int j = 0; j < 8; j++) o[j] = t[c + j][i * 32 + r];
            *(bf16x8*)&Wvt[(size_t)(n0 + i * 32 + r) * DD + k0 + c] = o;
        }
    }
}

// ---------------------------------------------------------------------------
// mm_reduce: Mp[e] = bf16(sum_c Mp4[c][e]), 4 elems/thread, 1024 blocks.
// ---------------------------------------------------------------------------
__global__ __launch_bounds__(256) void mm_reduce(const float* __restrict__ Mp4,
                                                 short* __restrict__ Mp)
{
    const size_t e = ((size_t)blockIdx.x * 256 + threadIdx.x) * 4;
    const size_t N = (size_t)DD * DD;
    float4 s = *(const float4*)&Mp4[e];
#pragma unroll
    for (int c = 1; c < 4; c++) {
        float4 p = *(const float4*)&Mp4[c * N + e];
        s.x += p.x; s.y += p.y; s.z += p.z; s.w += p.w;
    }
    bf16x4 o;
    o[0] = f2bf(s.x); o[1] = f2bf(s.y); o[2] = f2bf(s.z); o[3] = f2bf(s.w);
    *(bf16x4*)&Mp[e] = o;
}

// ---------------------------------------------------------------------------
// T = xb . M'^T (z=0) and V = xb . Wvt^T stored transposed (z=1).
// 256x128 tile, 8 waves, 3-slot rotating K64 pipeline, 2-deep counted
// prefetch, zero steady-state drains + swizzled LDS (all proven) —
// NEW: each iter's MFMA split into TWO fine phases (m201 template):
//   phase p: {ds_read 32-row half-tile (+bf once); BAR; setprio1;
//             16 MFMA; setprio0; BAR}
// bf fragments read in phase 0, reused in phase 1 (no extra LDS traffic).
// 5 uniform barriers/iter; vmcnt ledger identical to round 9/10.
// ---------------------------------------------------------------------------
__global__ __launch_bounds__(512) void tv_gemm(
    const short* __restrict__ xb, const short* __restrict__ Mp,
    const short* __restrict__ Wvt, short* __restrict__ T,
    short* __restrict__ Vt)
{
    __shared__ short lds[3 * 24576];                 // 3 slots x 48KB
    const int lin = blockIdx.x + 8 * blockIdx.y;     // [0,256) per z
    const int swz = (lin & 7) * 32 + (lin >> 3);     // bijective, 256 = 8*32
    const int n0 = (swz & 7) * 128;
    const int m0 = (swz >> 3) * 256;
    const int isv = blockIdx.z;
    const short* Bt = isv ? Wvt : Mp;
    const short* Ap = xb + (size_t)m0 * DD;
    const short* Bp = Bt + (size_t)n0 * DD;
    const int tid = threadIdx.x;
    const int lane = tid & 63, wave = tid >> 6;
    const int wm = (wave >> 1) * 64, wn = (wave & 1) * 64;
    const int fr = lane & 15;
    const int qa = (lane >> 4) ^ ((fr >> 1) & 3);    // swizzled k-quad slot
    f32x4 acc[4][4];
#pragma unroll
    for (int a = 0; a < 4; a++)
#pragma unroll
        for (int b = 0; b < 4; b++) acc[a][b] = (f32x4){0.f, 0.f, 0.f, 0.f};

    // prologue: K-tiles 0,1 -> slots 0,1 (12 loads/thread outstanding)
    stage_tile256(Ap, DD, Bp, DD, lds, tid);
    stage_tile256(Ap + 64, DD, Bp + 64, DD, lds + 24576, tid);
    for (int j = 0; j < 16; ++j) {
        if (j < 14)
            stage_tile256(Ap + (j + 2) * 64, DD, Bp + (j + 2) * 64, DD,
                          lds + ((j + 2) % 3) * 24576, tid);
        if (j < 14)       wait_vm12();
        else if (j == 14) wait_vm6();
        else              wait_vm0();
        barrier_raw();                               // slot-j data visible
        short* slot = lds + (j % 3) * 24576;
        const short* A0 = slot;                      // [ks][256][32], +8192/ks
        const short* B0 = slot + 16384;              // [ks][128][32], +4096/ks
        bf16x8 bf[8], af[4];
        // ---- phase 0: rows wm..wm+31 (+ all bf fragments, reused later) ----
#pragma unroll
        for (int ks = 0; ks < 2; ks++) {
#pragma unroll
            for (int t = 0; t < 4; t++)
                bf[ks * 4 + t] = *(const bf16x8*)
                    &B0[ks * 4096 + (wn + t * 16 + fr) * BK + qa * 8];
#pragma unroll
            for (int t = 0; t < 2; t++)
                af[ks * 2 + t] = *(const bf16x8*)
                    &A0[ks * 8192 + (wm + t * 16 + fr) * BK + qa * 8];
        }
        barrier_raw();
        __builtin_amdgcn_s_setprio(1);
#pragma unroll
        for (int ks = 0; ks < 2; ks++)
#pragma unroll
            for (int mt = 0; mt < 2; mt++)
#pragma unroll
                for (int nt = 0; nt < 4; nt++)
                    acc[mt][nt] = __builtin_amdgcn_mfma_f32_16x16x32_bf16(
                        af[ks * 2 + mt], bf[ks * 4 + nt], acc[mt][nt], 0, 0, 0);
        __builtin_amdgcn_s_setprio(0);
        barrier_raw();
        // ---- phase 1: rows wm+32..wm+63 (bf reused) ----
#pragma unroll
        for (int ks = 0; ks < 2; ks++)
#pragma unroll
            for (int t = 0; t < 2; t++)
                af[ks * 2 + t] = *(const bf16x8*)
                    &A0[ks * 8192 + (wm + 32 + t * 16 + fr) * BK + qa * 8];
        barrier_raw();
        __builtin_amdgcn_s_setprio(1);
#pragma unroll
        for (int ks = 0; ks < 2; ks++)
#pragma unroll
            for (int mt = 0; mt < 2; mt++)
#pragma unroll
                for (int nt = 0; nt < 4; nt++)
                    acc[2 + mt][nt] = __builtin_amdgcn_mfma_f32_16x16x32_bf16(
                        af[ks * 2 + mt], bf[ks * 4 + nt], acc[2 + mt][nt],
                        0, 0, 0);
        __builtin_amdgcn_s_setprio(0);
        barrier_raw();                               // WAR for slot reuse
    }

    const int quad = lane >> 4;
    if (!isv) {
#pragma unroll
        for (int mt = 0; mt < 4; mt++)
#pragma unroll
            for (int nt = 0; nt < 4; nt++)
#pragma unroll
                for (int r = 0; r < 4; r++) {
                    const size_t m = m0 + wm + mt * 16 + quad * 4 + r;
                    const size_t n = n0 + wn + nt * 16 + fr;
                    T[m * DD + n] = f2bf(acc[mt][nt][r]);
                }
    } else {
        const int bb = m0 >> 11;                   // batch of this m-tile
        const int s0 = (m0 & (SB - 1)) + wm + quad * 4;
        short* Vb = Vt + (size_t)bb * DD * SB;
#pragma unroll
        for (int mt = 0; mt < 4; mt++)
#pragma unroll
            for (int nt = 0; nt < 4; nt++) {
                const size_t n = n0 + wn + nt * 16 + fr;
                const size_t s = s0 + mt * 16;
                bf16x4 o;
#pragma unroll
                for (int r = 0; r < 4; r++) o[r] = f2bf(acc[mt][nt][r]);
                *(bf16x4*)&Vb[n * SB + s] = o;
            }
    }
}

// ---------------------------------------------------------------------------
// Scores at BN=64: triangular grid 272 tiles/batch -> 1088 blocks (4.25/CU).
// cum(qt) = qt*(qt+1); kt in [0, 2qt+2). XCD swizzle: 272 = 8*34.
// Sc[b][q][j] = scale * T_b[q,:] . xb_b[j,:], bf16 out. Swizzled LDS.
// ---------------------------------------------------------------------------
__global__ __launch_bounds__(256) void scores_mfma(
    const short* __restrict__ T, const short* __restrict__ xb,
    short* __restrict__ Sc)
{
    const int bx = blockIdx.x;
    const int idx = (bx & 7) * 34 + (bx >> 3);       // bijective, 272 = 8*34
    int qt = (int)((__fsqrt_rn(4.f * idx + 1.f) - 1.f) * 0.5f);
    while ((qt + 1) * (qt + 2) <= idx) qt++;
    while (qt * (qt + 1) > idx) qt--;
    const int kt = idx - qt * (qt + 1);              // [0, 2qt+2)
    const int qm0 = qt * BM;
    const int kn0 = kt * 64;
    const int b = blockIdx.y;
    __shared__ short As[2 * BM * BK], Bs[2 * 64 * BK];
    const short* Tq = T + (size_t)b * SB * DD + (size_t)qm0 * DD;
    const short* Xk = xb + (size_t)b * SB * DD + (size_t)kn0 * DD;
    short* Sb = Sc + (size_t)b * SB * SB;
    const int tid = threadIdx.x;
    const int lane = tid & 63, wave = tid >> 6;
    f32x4 acc[2][4];
#pragma unroll
    for (int a = 0; a < 2; a++)
#pragma unroll
        for (int c = 0; c < 4; c++) acc[a][c] = (f32x4){0.f, 0.f, 0.f, 0.f};
    for (int k0 = 0; k0 < DD; k0 += 2 * BK) {
        stage128x32(Tq + k0, DD, As, tid);
        stage128x32(Tq + k0 + BK, DD, As + BM * BK, tid);
        stage64x32(Xk + k0, DD, Bs, tid);
        stage64x32(Xk + k0 + BK, DD, Bs + 64 * BK, tid);
        __syncthreads();
        mfma_step_pv_swz(As, Bs, acc, lane, wave);
        mfma_step_pv_swz(As + BM * BK, Bs + 64 * BK, acc, lane, wave);
        __syncthreads();
    }
    const int fr = lane & 15, quad = lane >> 4;
    const float scale = 0.03125f;  // 1/sqrt(1024)
#pragma unroll
    for (int mt = 0; mt < 2; mt++)
#pragma unroll
        for (int nt = 0; nt < 4; nt++)
#pragma unroll
            for (int r = 0; r < 4; r++) {
                const size_t q = qm0 + wave * 32 + mt * 16 + quad * 4 + r;
                const size_t k = kn0 + nt * 16 + fr;
                Sb[q * SB + k] = f2bf(acc[mt][nt][r] * scale);
            }
}

// ---------------------------------------------------------------------------
// Causal softmax on bf16 scores, in place (row stride SB shorts). Row i only
// touches j < jlim = (i/128+1)*128 — pv reads exactly k < (qt+1)*128.
// Vectorized: 2048 elems = 256 threads x bf16x8; masked segments skip the
// load entirely.
// ---------------------------------------------------------------------------
__global__ __launch_bounds__(256) void softmax_kernel(short* __restrict__ Sc)
{
    const int row = blockIdx.x;
    const int i = row & (SB - 1);
    const int jlim = ((i >> 7) + 1) << 7;
    short* r = Sc + (size_t)row * SB;
    const int t = threadIdx.x;
    const int lane = t & 63, wave = t >> 6;
    __shared__ float red[8];

    const int j0 = t * 8;
    bf16x8 in = {0, 0, 0, 0, 0, 0, 0, 0};
    if (j0 <= i) in = *(const bf16x8*)&r[j0];
    float v[8];
    float mx = -1e30f;
#pragma unroll
    for (int e = 0; e < 8; e++) {
        const float s = (j0 + e <= i) ? bf2f((unsigned short)in[e]) : -1e30f;
        v[e] = s;
        mx = fmaxf(mx, s);
    }
#pragma unroll
    for (int o = 32; o > 0; o >>= 1) mx = fmaxf(mx, __shfl_down(mx, o));
    if (lane == 0) red[wave] = mx;
    __syncthreads();
    mx = fmaxf(fmaxf(red[0], red[1]), fmaxf(red[2], red[3]));

    float sum = 0.f;
#pragma unroll
    for (int e = 0; e < 8; e++) {
        const float x = (j0 + e <= i) ? __expf(v[e] - mx) : 0.f;
        v[e] = x;
        sum += x;
    }
#pragma unroll
    for (int o = 32; o > 0; o >>= 1) sum += __shfl_down(sum, o);
    if (lane == 0) red[4 + wave] = sum;
    __syncthreads();
    const float inv = 1.0f / (red[4] + red[5] + red[6] + red[7]);
    if (j0 < jlim) {
        bf16x8 o;
#pragma unroll
        for (int e = 0; e < 8; e++) o[e] = f2bf(v[e] * inv);
        *(bf16x8*)&r[j0] = o;
    }
}

// ---------------------------------------------------------------------------
// PV, balanced pairing at BN=64, K64 counted-prefetch double-buffer (proven
// round 8): 2 barriers per K64, vmcnt(6), uniform 34 K64-iters/block.
// Swizzled LDS.
// ---------------------------------------------------------------------------
__global__ __launch_bounds__(256) void pv_mfma(
    const short* __restrict__ P, const short* __restrict__ Vt,
    float* __restrict__ O)
{
    __shared__ short As[4 * BM * BK];   // [dbuf][2 subtiles][128][32] = 32 KB
    __shared__ short Bs[4 * 64 * BK];   // [dbuf][2 subtiles][64][32]  = 16 KB
    const int n0 = blockIdx.x * 64;
    const int pair = blockIdx.y;           // 0..7
    const int b = blockIdx.z;
    const short* Pb = P + (size_t)b * SB * SB;
    const short* Vb = Vt + (size_t)b * DD * SB;
    float* Ob = O + (size_t)b * SB * DD;
    const int tid = threadIdx.x;
    const int lane = tid & 63, wave = tid >> 6;
    const int fr = lane & 15, quad = lane >> 4;
    for (int half = 0; half < 2; ++half) {
        const int qt = half ? (15 - pair) : pair;   // short tile first: its
        const int qm0 = qt * BM;                    // V k-range is a prefix of
        const int nj = (qt + 1) * 2;                // K64 tiles (kend/64)
        const short* Pq = Pb + (size_t)qm0 * SB;
        const short* Vn = Vb + (size_t)n0 * SB;
        f32x4 acc[2][4];
#pragma unroll
        for (int a = 0; a < 2; a++)
#pragma unroll
            for (int c = 0; c < 4; c++) acc[a][c] = (f32x4){0.f, 0.f, 0.f, 0.f};
        // prologue: tile 0 into slot 0 (6 loads/thread)
        stage128x32(Pq, SB, As, tid);
        stage128x32(Pq + BK, SB, As + BM * BK, tid);
        stage64x32(Vn, SB, Bs, tid);
        stage64x32(Vn + BK, SB, Bs + 64 * BK, tid);
        for (int j = 0; j < nj; ++j) {
            const int cur = j & 1;
            const short* as = As + cur * (2 * BM * BK);
            const short* bs = Bs + cur * (2 * 64 * BK);
            if (j + 1 < nj) {
                const int off = (j + 1) * 64;
                short* an = As + (cur ^ 1) * (2 * BM * BK);
                short* bn = Bs + (cur ^ 1) * (2 * 64 * BK);
                stage128x32(Pq + off, SB, an, tid);
                stage128x32(Pq + off + BK, SB, an + BM * BK, tid);
                stage64x32(Vn + off, SB, bn, tid);
                stage64x32(Vn + off + BK, SB, bn + 64 * BK, tid);
                wait_vm6();
            } else {
                wait_vm0();
            }
            barrier_raw();
            mfma_step_pv_swz(as, bs, acc, lane, wave);
            mfma_step_pv_swz(as + BM * BK, bs + 64 * BK, acc, lane, wave);
            barrier_raw();
        }
#pragma unroll
        for (int mt = 0; mt < 2; mt++)
#pragma unroll
            for (int nt = 0; nt < 4; nt++)
#pragma unroll
                for (int r = 0; r < 4; r++) {
                    const size_t q = qm0 + wave * 32 + mt * 16 + quad * 4 + r;
                    const size_t n = n0 + nt * 16 + fr;
                    Ob[q * DD + n] = acc[mt][nt][r];
                }
    }
}

extern "C" void kernel_launch(void* const* d_in, const int* in_sizes, int n_in,
                              void* d_out, int out_size, void* d_ws, size_t ws_size,
                              hipStream_t stream)
{
    const float* x  = (const float*)d_in[0];
    const float* Wq = (const float*)d_in[1];
    const float* Wk = (const float*)d_in[2];
    const float* Wv = (const float*)d_in[3];
    float* out = (float*)d_out;

    // ws layout (~105 MB): [xb 16.8M][T 16.8M][Vt 16.8M][Sc 33.6M][Pp 16.8M]
    // [Wvt 2M][Mp 2M].  Mp4 (16.8 MB of fp32 mm partials) ALIASES the Sc
    // region: written by prep_mm, consumed by mm_reduce, then Sc overwrites
    // it in scores_mfma — all strictly ordered on the serial stream.
    const size_t XE = (size_t)NB * SB * DD;   // 8.39M elems
    const size_t WE = (size_t)DD * DD;        // 1.05M elems
    short* xb  = (short*)d_ws;
    short* T   = xb + XE;
    short* Vt  = T + XE;
    short* Sc  = Vt + XE;                     // NB*SB*SB shorts
    float* Pp  = (float*)(Sc + (size_t)NB * SB * SB);
    short* Wvt = (short*)(Pp + (size_t)NB * 1024 * DD);
    short* Mp  = Wvt + WE;
    float* Mp4 = (float*)Sc;                  // 4*WE fp32, dead before scores

    prep_mm<<<dim3(256 + 4096 + 256), 256, 0, stream>>>(
        x, Wq, Wk, Wv, xb, Wvt, Mp4);
    mm_reduce<<<dim3(1024), 256, 0, stream>>>(Mp4, Mp);
    tv_gemm<<<dim3(8, 32, 2), 512, 0, stream>>>(xb, Mp, Wvt, T, Vt);
    scores_mfma<<<dim3(272, NB), 256, 0, stream>>>(T, xb, Sc);
    softmax_kernel<<<dim3(NB * SB), 256, 0, stream>>>(Sc);
    pv_mfma<<<dim3(DD / 64, 8, NB), 256, 0, stream>>>(Sc, Vt, out);
}

// Round 12
// 222.614 us; speedup vs baseline: 1.0294x; 1.0294x over previous
//
#include <hip/hip_runtime.h>
#include <hip/hip_bf16.h>

// x [4,2048,1024] fp32; Wq/Wk/Wv [1024,1024] fp32. Causal attention.
// Algebra: scores = x Wq Wk^T x^T = T x^T with T = x M'^T, M' = Wk Wq^T.
//
// LDS swizzle (proven, conflicts 4.19M -> 0): data for k-quad q of row r sits
// at qslot = q ^ ((r>>1)&3); applied on the GLOBAL source column
// (global_load_lds writes linearly), reads XOR the same term.
// This round: tv_gemm geometry -> 256x256 tile, wave tile 128x64 (acc[8][4],
// reads/MFMA 0.375), on the twice-proven 2-slot counted-vmcnt dbuf skeleton.
#define NB 4
#define SB 2048
#define DD 1024
#define BM 128
#define BN 128
#define BK 32

typedef __attribute__((ext_vector_type(8))) short bf16x8;
typedef __attribute__((ext_vector_type(4))) short bf16x4;
typedef __attribute__((ext_vector_type(4))) float f32x4;
typedef unsigned int u32;

__device__ __forceinline__ float bf2f(unsigned short u) {
    return __uint_as_float(((u32)u) << 16);
}
__device__ __forceinline__ short f2bf(float f) {
    u32 u = __float_as_uint(f);
    u32 r = (u + 0x7fffu + ((u >> 16) & 1u)) >> 16;
    return (short)r;
}

// Counted waits + raw barrier: prefetched tiles stay in flight across
// barriers; no full drain in steady state.
__device__ __forceinline__ void wait_vm8() {
    asm volatile("s_waitcnt vmcnt(8)" ::: "memory");
}
__device__ __forceinline__ void wait_vm6() {
    asm volatile("s_waitcnt vmcnt(6)" ::: "memory");
}
__device__ __forceinline__ void wait_vm0() {
    asm volatile("s_waitcnt vmcnt(0)" ::: "memory");
}
__device__ __forceinline__ void barrier_raw() {
    __builtin_amdgcn_s_barrier();
    asm volatile("" ::: "memory");   // no LDS access motion across barrier
}

// ---------------------------------------------------------------------------
// UNSWIZZLED MFMA tile step (prep_mm only — matches stage_f32_128x32 writes).
// ---------------------------------------------------------------------------
__device__ __forceinline__ void mfma_step(const short* As, const short* Bs,
                                          f32x4 (&acc)[4][4], int lane, int wave)
{
    const int wm = (wave >> 1) * 64, wn = (wave & 1) * 64;
    const int fr = lane & 15;
    const int quad = lane >> 4;
    bf16x8 af[4], bf[4];
#pragma unroll
    for (int t = 0; t < 4; t++) {
        af[t] = *(const bf16x8*)&As[(wm + t * 16 + fr) * BK + quad * 8];
        bf[t] = *(const bf16x8*)&Bs[(wn + t * 16 + fr) * BK + quad * 8];
    }
#pragma unroll
    for (int mt = 0; mt < 4; mt++)
#pragma unroll
        for (int nt = 0; nt < 4; nt++)
            acc[mt][nt] = __builtin_amdgcn_mfma_f32_16x16x32_bf16(
                af[mt], bf[nt], acc[mt][nt], 0, 0, 0);
}

// 128 x BN=64 swizzled tile step: wave owns 32-row m-slice, full 64-col n.
__device__ __forceinline__ void mfma_step_pv_swz(const short* As,
                                                 const short* Bs,
                                                 f32x4 (&acc)[2][4], int lane,
                                                 int wave)
{
    const int wm = wave * 32;
    const int fr = lane & 15;
    const int qa = (lane >> 4) ^ ((fr >> 1) & 3);
    bf16x8 af[2], bf[4];
#pragma unroll
    for (int t = 0; t < 2; t++)
        af[t] = *(const bf16x8*)&As[(wm + t * 16 + fr) * BK + qa * 8];
#pragma unroll
    for (int t = 0; t < 4; t++)
        bf[t] = *(const bf16x8*)&Bs[(t * 16 + fr) * BK + qa * 8];
#pragma unroll
    for (int mt = 0; mt < 2; mt++)
#pragma unroll
        for (int nt = 0; nt < 4; nt++)
            acc[mt][nt] = __builtin_amdgcn_mfma_f32_16x16x32_bf16(
                af[mt], bf[nt], acc[mt][nt], 0, 0, 0);
}

// tv 256x256: wave tile 128x64 (wr=wave>>2, wc=wave&3), one K32 sub-tile.
// As: [256][32] sub-tile base; Bs: [256][32] sub-tile base (B rows = n-cols).
__device__ __forceinline__ void mfma_step256_swz(const short* As,
                                                 const short* Bs,
                                                 f32x4 (&acc)[8][4], int lane,
                                                 int wave)
{
    const int wm = (wave >> 2) * 128;
    const int wn = (wave & 3) * 64;
    const int fr = lane & 15;
    const int qa = (lane >> 4) ^ ((fr >> 1) & 3);
    bf16x8 af[8], bf[4];
#pragma unroll
    for (int t = 0; t < 8; t++)
        af[t] = *(const bf16x8*)&As[(wm + t * 16 + fr) * BK + qa * 8];
#pragma unroll
    for (int t = 0; t < 4; t++)
        bf[t] = *(const bf16x8*)&Bs[(wn + t * 16 + fr) * BK + qa * 8];
#pragma unroll
    for (int mt = 0; mt < 8; mt++)
#pragma unroll
        for (int nt = 0; nt < 4; nt++)
            acc[mt][nt] = __builtin_amdgcn_mfma_f32_16x16x32_bf16(
                af[mt], bf[nt], acc[mt][nt], 0, 0, 0);
}

// bf16 staging, SWIZZLED SOURCE: LDS dest linear; lane fetches global k-quad
// (lane&3)^((lane>>3)&3) so LDS slot (row,qslot) holds quad qslot^((row>>1)&3).
__device__ __forceinline__ void stage128x32(const short* __restrict__ g, int ld,
                                            short* lds, int tid) {
    const int wave = tid >> 6, lane = tid & 63;
    const int r = lane >> 2;
    const int c = ((lane & 3) ^ ((lane >> 3) & 3)) * 8;
#pragma unroll
    for (int i = 0; i < 2; i++) {
        const int chunk = wave * 2 + i;
        const short* gp = g + (size_t)(chunk * 16 + r) * ld + c;
        __builtin_amdgcn_global_load_lds(
            (const __attribute__((address_space(1))) u32*)gp,
            (__attribute__((address_space(3))) u32*)(lds + chunk * 512 + lane * 8),
            16, 0, 0);
    }
}

// 64x32 tile, swizzled source: one 16B global_load_lds per thread.
__device__ __forceinline__ void stage64x32(const short* __restrict__ g, int ld,
                                           short* lds, int tid) {
    const int wave = tid >> 6, lane = tid & 63;
    const int r = lane >> 2;
    const int c = ((lane & 3) ^ ((lane >> 3) & 3)) * 8;
    const short* gp = g + (size_t)(wave * 16 + r) * ld + c;
    __builtin_amdgcn_global_load_lds(
        (const __attribute__((address_space(1))) u32*)gp,
        (__attribute__((address_space(3))) u32*)(lds + wave * 512 + lane * 8),
        16, 0, 0);
}

// ---------------------------------------------------------------------------
// Stage 256 rows x 64 k of one matrix into [2ks][256][32] (32KB), swizzled
// source, linear LDS dest. 4 loads/thread at 512 threads.
// dest offset = ks*8192 + (i&1)*4096 + w*512 + l*8  ==  ks*8192 + row*32 + col8
// with row = (i&1)*128 + w*16 + (l>>2); (row>>1)&3 == (l>>3)&3 (all proven).
// ---------------------------------------------------------------------------
__device__ __forceinline__ void stage256x64(const short* __restrict__ g, int ld,
                                            short* base, int tid) {
    const int w = tid >> 6, l = tid & 63;
    const int lr = l >> 2;
    const int lc = ((l & 3) ^ ((l >> 3) & 3)) * 8;
#pragma unroll
    for (int i = 0; i < 4; i++) {
        const int ks = i >> 1;
        const int row = (i & 1) * 128 + w * 16 + lr;
        const short* gp = g + (size_t)row * ld + ks * 32 + lc;
        __builtin_amdgcn_global_load_lds(
            (const __attribute__((address_space(1))) u32*)gp,
            (__attribute__((address_space(3))) u32*)(base + i * 4096 + w * 512 + l * 8),
            16, 0, 0);
    }
}

// fp32 source staging: load fp32, convert, ds_write (prep_mm only; unswizzled,
// matched with the unswizzled mfma_step).
__device__ __forceinline__ void stage_f32_128x32(const float* __restrict__ g,
                                                 int ld, short* lds, int tid) {
    const int r = tid >> 1;
    const int c = (tid & 1) * 16;
    const float* gp = &g[(size_t)r * ld + c];
    float4 v0 = *(const float4*)(gp + 0);
    float4 v1 = *(const float4*)(gp + 4);
    float4 v2 = *(const float4*)(gp + 8);
    float4 v3 = *(const float4*)(gp + 12);
    bf16x8 o0, o1;
    o0[0] = f2bf(v0.x); o0[1] = f2bf(v0.y); o0[2] = f2bf(v0.z); o0[3] = f2bf(v0.w);
    o0[4] = f2bf(v1.x); o0[5] = f2bf(v1.y); o0[6] = f2bf(v1.z); o0[7] = f2bf(v1.w);
    o1[0] = f2bf(v2.x); o1[1] = f2bf(v2.y); o1[2] = f2bf(v2.z); o1[3] = f2bf(v2.w);
    o1[4] = f2bf(v3.x); o1[5] = f2bf(v3.y); o1[6] = f2bf(v3.z); o1[7] = f2bf(v3.w);
    *(bf16x8*)&lds[r * BK + c] = o0;
    *(bf16x8*)&lds[r * BK + c + 8] = o1;
}

// ---------------------------------------------------------------------------
// Fused prep + split-k mm:
//   bx in [0,256):       M' partials: chunk c=bx>>6 computes
//                        Mp4[c][m][n] = sum_{k in c*256..+256} Wk[m][k]Wq[n][k]
//   bx in [256,4352):    cast x fp32->bf16 (8 elem/thr)
//   bx in [4352,4608):   cast+transpose Wv -> Wvt[n][k]
// ---------------------------------------------------------------------------
__global__ __launch_bounds__(256) void prep_mm(
    const float* __restrict__ x, const float* __restrict__ Wq,
    const float* __restrict__ Wk, const float* __restrict__ Wv,
    short* __restrict__ xb, short* __restrict__ Wvt, float* __restrict__ Mp4)
{
    __shared__ short As[BM * BK], Bs[BN * BK];
    __shared__ short t[64][65];
    const int bx = blockIdx.x;
    const int tid = threadIdx.x;
    if (bx < 256) {
        const int ch = bx >> 6;            // split-k chunk, 256 wide
        const int t64 = bx & 63;
        const int m0 = (t64 >> 3) * BM;
        const int n0 = (t64 & 7) * BN;
        const int kbase = ch * 256;
        const int lane = tid & 63, wave = tid >> 6;
        f32x4 acc[4][4];
#pragma unroll
        for (int a = 0; a < 4; a++)
#pragma unroll
            for (int b = 0; b < 4; b++) acc[a][b] = (f32x4){0.f, 0.f, 0.f, 0.f};
        for (int k0 = 0; k0 < 256; k0 += BK) {
            stage_f32_128x32(Wk + (size_t)m0 * DD + kbase + k0, DD, As, tid);
            stage_f32_128x32(Wq + (size_t)n0 * DD + kbase + k0, DD, Bs, tid);
            __syncthreads();
            mfma_step(As, Bs, acc, lane, wave);
            __syncthreads();
        }
        const int wm = (wave >> 1) * 64, wn = (wave & 1) * 64;
        const int fr = lane & 15, quad = lane >> 4;
        float* Mc = Mp4 + (size_t)ch * DD * DD;
#pragma unroll
        for (int mt = 0; mt < 4; mt++)
#pragma unroll
            for (int nt = 0; nt < 4; nt++)
#pragma unroll
                for (int r = 0; r < 4; r++) {
                    const size_t m = m0 + wm + mt * 16 + quad * 4 + r;
                    const size_t n = n0 + wn + nt * 16 + fr;
                    Mc[m * DD + n] = acc[mt][nt][r];
                }
        return;
    }
    if (bx < 4352) {
        const size_t i = ((size_t)(bx - 256) * 256 + tid) * 8;
        float4 a = *(const float4*)&x[i];
        float4 b = *(const float4*)&x[i + 4];
        bf16x8 o;
        o[0] = f2bf(a.x); o[1] = f2bf(a.y); o[2] = f2bf(a.z); o[3] = f2bf(a.w);
        o[4] = f2bf(b.x); o[5] = f2bf(b.y); o[6] = f2bf(b.z); o[7] = f2bf(b.w);
        *(bf16x8*)&xb[i] = o;
        return;
    }
    const int rr = bx - 4352;
    const int k0 = (rr & 15) * 64;
    const int n0 = (rr >> 4) * 64;
    {
        const int r = tid >> 4;
        const int c = (tid & 15) * 4;
#pragma unroll
        for (int i = 0; i < 4; i++) {
            float4 v = *(const float4*)&Wv[(size_t)(k0 + i * 16 + r) * DD + n0 + c];
            t[i * 16 + r][c + 0] = f2bf(v.x);
            t[i * 16 + r][c + 1] = f2bf(v.y);
            t[i * 16 + r][c + 2] = f2bf(v.z);
            t[i * 16 + r][c + 3] = f2bf(v.w);
        }
    }
    __syncthreads();
    {
        const int r = tid >> 3;
        const int c = (tid & 7) * 8;
#pragma unroll
        for (int i = 0; i < 2; i++) {
            bf16x8 o;
#pragma unroll
            for (int j = 0; j < 8; j++) o[j] = t[c + j][i * 32 + r];
            *(bf16x8*)&Wvt[(size_t)(n0 + i * 32 + r) * DD + k0 + c] = o;
        }
    }
}

// ---------------------------------------------------------------------------
// mm_reduce: Mp[e] = bf16(sum_c Mp4[c][e]), 4 elems/thread, 1024 blocks.
// ---------------------------------------------------------------------------
__global__ __launch_bounds__(256) void mm_reduce(const float* __restrict__ Mp4,
                                                 short* __restrict__ Mp)
{
    const size_t e = ((size_t)blockIdx.x * 256 + threadIdx.x) * 4;
    const size_t N = (size_t)DD * DD;
    float4 s = *(const float4*)&Mp4[e];
#pragma unroll
    for (int c = 1; c < 4; c++) {
        float4 p = *(const float4*)&Mp4[c * N + e];
        s.x += p.x; s.y += p.y; s.z += p.z; s.w += p.w;
    }
    bf16x4 o;
    o[0] = f2bf(s.x); o[1] = f2bf(s.y); o[2] = f2bf(s.z); o[3] = f2bf(s.w);
    *(bf16x4*)&Mp[e] = o;
}

// ---------------------------------------------------------------------------
// T = xb . M'^T (z=0) and V = xb . Wvt^T stored transposed (z=1).
// 256x256 tile, 8 waves as 2m x 4n (wave tile 128x64, acc[8][4] = 128 VGPR,
// reads/MFMA 0.375). Sync skeleton = twice-proven 2-slot counted dbuf:
//   prologue: stage tile0 (8 loads/thr);
//   iter j: stage tile j+1 -> slot^1; vmcnt(8) retires tile j; barrier;
//           64 MFMA (2 K32 sub-steps, setprio-wrapped); barrier.
// LDS 2 x 64KB = 128KB -> 1 block/CU; grid 4x32x2 = 256 blocks = ONE wave.
// XCD: lin = bx+4*by (+128z == 0 mod 8) -> XCD = lin%8; swz gives each XCD
// 4 contiguous m-panels x all 4 n (A 2MB + B 2MB = one L2).
// ---------------------------------------------------------------------------
__global__ __launch_bounds__(512) void tv_gemm(
    const short* __restrict__ xb, const short* __restrict__ Mp,
    const short* __restrict__ Wvt, short* __restrict__ T,
    short* __restrict__ Vt)
{
    __shared__ short lds[2 * 32768];                 // 2 slots x 64KB
    const int lin = blockIdx.x + 4 * blockIdx.y;     // [0,128) per z
    const int swz = (lin & 7) * 16 + (lin >> 3);     // bijective, 128 = 8*16
    const int n0 = (swz & 3) * 256;
    const int m0 = (swz >> 2) * 256;
    const int isv = blockIdx.z;
    const short* Bt = isv ? Wvt : Mp;
    const short* Ap = xb + (size_t)m0 * DD;
    const short* Bp = Bt + (size_t)n0 * DD;
    const int tid = threadIdx.x;
    const int lane = tid & 63, wave = tid >> 6;
    f32x4 acc[8][4];
#pragma unroll
    for (int a = 0; a < 8; a++)
#pragma unroll
        for (int b = 0; b < 4; b++) acc[a][b] = (f32x4){0.f, 0.f, 0.f, 0.f};

    // prologue: tile 0 -> slot 0 (A then B; 8 loads/thread outstanding)
    stage256x64(Ap, DD, lds, tid);
    stage256x64(Bp, DD, lds + 16384, tid);
    for (int j = 0; j < 16; ++j) {
        const int cur = j & 1;
        short* slot = lds + cur * 32768;
        if (j < 15) {
            short* nxt = lds + (cur ^ 1) * 32768;
            stage256x64(Ap + (j + 1) * 64, DD, nxt, tid);
            stage256x64(Bp + (j + 1) * 64, DD, nxt + 16384, tid);
            wait_vm8();
        } else {
            wait_vm0();
        }
        barrier_raw();
        __builtin_amdgcn_s_setprio(1);
        mfma_step256_swz(slot, slot + 16384, acc, lane, wave);          // ks=0
        mfma_step256_swz(slot + 8192, slot + 16384 + 8192, acc, lane, wave); // ks=1
        __builtin_amdgcn_s_setprio(0);
        barrier_raw();
    }

    const int wm = (wave >> 2) * 128, wn = (wave & 3) * 64;
    const int fr = lane & 15, quad = lane >> 4;
    if (!isv) {
#pragma unroll
        for (int mt = 0; mt < 8; mt++)
#pragma unroll
            for (int nt = 0; nt < 4; nt++)
#pragma unroll
                for (int r = 0; r < 4; r++) {
                    const size_t m = m0 + wm + mt * 16 + quad * 4 + r;
                    const size_t n = n0 + wn + nt * 16 + fr;
                    T[m * DD + n] = f2bf(acc[mt][nt][r]);
                }
    } else {
        const int bb = m0 >> 11;                   // batch of this m-tile
        const int s0 = (m0 & (SB - 1)) + wm + quad * 4;
        short* Vb = Vt + (size_t)bb * DD * SB;
#pragma unroll
        for (int mt = 0; mt < 8; mt++)
#pragma unroll
            for (int nt = 0; nt < 4; nt++) {
                const size_t n = n0 + wn + nt * 16 + fr;
                const size_t s = s0 + mt * 16;
                bf16x4 o;
#pragma unroll
                for (int r = 0; r < 4; r++) o[r] = f2bf(acc[mt][nt][r]);
                *(bf16x4*)&Vb[n * SB + s] = o;
            }
    }
}

// ---------------------------------------------------------------------------
// Scores at BN=64: triangular grid 272 tiles/batch -> 1088 blocks (4.25/CU).
// cum(qt) = qt*(qt+1); kt in [0, 2qt+2). XCD swizzle: 272 = 8*34.
// Sc[b][q][j] = scale * T_b[q,:] . xb_b[j,:], bf16 out. Swizzled LDS.
// ---------------------------------------------------------------------------
__global__ __launch_bounds__(256) void scores_mfma(
    const short* __restrict__ T, const short* __restrict__ xb,
    short* __restrict__ Sc)
{
    const int bx = blockIdx.x;
    const int idx = (bx & 7) * 34 + (bx >> 3);       // bijective, 272 = 8*34
    int qt = (int)((__fsqrt_rn(4.f * idx + 1.f) - 1.f) * 0.5f);
    while ((qt + 1) * (qt + 2) <= idx) qt++;
    while (qt * (qt + 1) > idx) qt--;
    const int kt = idx - qt * (qt + 1);              // [0, 2qt+2)
    const int qm0 = qt * BM;
    const int kn0 = kt * 64;
    const int b = blockIdx.y;
    __shared__ short As[2 * BM * BK], Bs[2 * 64 * BK];
    const short* Tq = T + (size_t)b * SB * DD + (size_t)qm0 * DD;
    const short* Xk = xb + (size_t)b * SB * DD + (size_t)kn0 * DD;
    short* Sb = Sc + (size_t)b * SB * SB;
    const int tid = threadIdx.x;
    const int lane = tid & 63, wave = tid >> 6;
    f32x4 acc[2][4];
#pragma unroll
    for (int a = 0; a < 2; a++)
#pragma unroll
        for (int c = 0; c < 4; c++) acc[a][c] = (f32x4){0.f, 0.f, 0.f, 0.f};
    for (int k0 = 0; k0 < DD; k0 += 2 * BK) {
        stage128x32(Tq + k0, DD, As, tid);
        stage128x32(Tq + k0 + BK, DD, As + BM * BK, tid);
        stage64x32(Xk + k0, DD, Bs, tid);
        stage64x32(Xk + k0 + BK, DD, Bs + 64 * BK, tid);
        __syncthreads();
        mfma_step_pv_swz(As, Bs, acc, lane, wave);
        mfma_step_pv_swz(As + BM * BK, Bs + 64 * BK, acc, lane, wave);
        __syncthreads();
    }
    const int fr = lane & 15, quad = lane >> 4;
    const float scale = 0.03125f;  // 1/sqrt(1024)
#pragma unroll
    for (int mt = 0; mt < 2; mt++)
#pragma unroll
        for (int nt = 0; nt < 4; nt++)
#pragma unroll
            for (int r = 0; r < 4; r++) {
                const size_t q = qm0 + wave * 32 + mt * 16 + quad * 4 + r;
                const size_t k = kn0 + nt * 16 + fr;
                Sb[q * SB + k] = f2bf(acc[mt][nt][r] * scale);
            }
}

// ---------------------------------------------------------------------------
// Causal softmax on bf16 scores, in place (row stride SB shorts). Row i only
// touches j < jlim = (i/128+1)*128 — pv reads exactly k < (qt+1)*128.
// Vectorized: 2048 elems = 256 threads x bf16x8; masked segments skip the
// load entirely.
// ---------------------------------------------------------------------------
__global__ __launch_bounds__(256) void softmax_kernel(short* __restrict__ Sc)
{
    const int row = blockIdx.x;
    const int i = row & (SB - 1);
    const int jlim = ((i >> 7) + 1) << 7;
    short* r = Sc + (size_t)row * SB;
    const int t = threadIdx.x;
    const int lane = t & 63, wave = t >> 6;
    __shared__ float red[8];

    const int j0 = t * 8;
    bf16x8 in = {0, 0, 0, 0, 0, 0, 0, 0};
    if (j0 <= i) in = *(const bf16x8*)&r[j0];
    float v[8];
    float mx = -1e30f;
#pragma unroll
    for (int e = 0; e < 8; e++) {
        const float s = (j0 + e <= i) ? bf2f((unsigned short)in[e]) : -1e30f;
        v[e] = s;
        mx = fmaxf(mx, s);
    }
#pragma unroll
    for (int o = 32; o > 0; o >>= 1) mx = fmaxf(mx, __shfl_down(mx, o));
    if (lane == 0) red[wave] = mx;
    __syncthreads();
    mx = fmaxf(fmaxf(red[0], red[1]), fmaxf(red[2], red[3]));

    float sum = 0.f;
#pragma unroll
    for (int e = 0; e < 8; e++) {
        const float x = (j0 + e <= i) ? __expf(v[e] - mx) : 0.f;
        v[e] = x;
        sum += x;
    }
#pragma unroll
    for (int o = 32; o > 0; o >>= 1) sum += __shfl_down(sum, o);
    if (lane == 0) red[4 + wave] = sum;
    __syncthreads();
    const float inv = 1.0f / (red[4] + red[5] + red[6] + red[7]);
    if (j0 < jlim) {
        bf16x8 o;
#pragma unroll
        for (int e = 0; e < 8; e++) o[e] = f2bf(v[e] * inv);
        *(bf16x8*)&r[j0] = o;
    }
}

// ---------------------------------------------------------------------------
// PV, balanced pairing at BN=64, K64 counted-prefetch double-buffer (proven
// round 8): 2 barriers per K64, vmcnt(6), uniform 34 K64-iters/block.
// Swizzled LDS.
// ---------------------------------------------------------------------------
__global__ __launch_bounds__(256) void pv_mfma(
    const short* __restrict__ P, const short* __restrict__ Vt,
    float* __restrict__ O)
{
    __shared__ short As[4 * BM * BK];   // [dbuf][2 subtiles][128][32] = 32 KB
    __shared__ short Bs[4 * 64 * BK];   // [dbuf][2 subtiles][64][32]  = 16 KB
    const int n0 = blockIdx.x * 64;
    const int pair = blockIdx.y;           // 0..7
    const int b = blockIdx.z;
    const short* Pb = P + (size_t)b * SB * SB;
    const short* Vb = Vt + (size_t)b * DD * SB;
    float* Ob = O + (size_t)b * SB * DD;
    const int tid = threadIdx.x;
    const int lane = tid & 63, wave = tid >> 6;
    const int fr = lane & 15, quad = lane >> 4;
    for (int half = 0; half < 2; ++half) {
        const int qt = half ? (15 - pair) : pair;   // short tile first: its
        const int qm0 = qt * BM;                    // V k-range is a prefix of
        const int nj = (qt + 1) * 2;                // K64 tiles (kend/64)
        const short* Pq = Pb + (size_t)qm0 * SB;
        const short* Vn = Vb + (size_t)n0 * SB;
        f32x4 acc[2][4];
#pragma unroll
        for (int a = 0; a < 2; a++)
#pragma unroll
            for (int c = 0; c < 4; c++) acc[a][c] = (f32x4){0.f, 0.f, 0.f, 0.f};
        // prologue: tile 0 into slot 0 (6 loads/thread)
        stage128x32(Pq, SB, As, tid);
        stage128x32(Pq + BK, SB, As + BM * BK, tid);
        stage64x32(Vn, SB, Bs, tid);
        stage64x32(Vn + BK, SB, Bs + 64 * BK, tid);
        for (int j = 0; j < nj; ++j) {
            const int cur = j & 1;
            const short* as = As + cur * (2 * BM * BK);
            const short* bs = Bs + cur * (2 * 64 * BK);
            if (j + 1 < nj) {
                const int off = (j + 1) * 64;
                short* an = As + (cur ^ 1) * (2 * BM * BK);
                short* bn = Bs + (cur ^ 1) * (2 * 64 * BK);
                stage128x32(Pq + off, SB, an, tid);
                stage128x32(Pq + off + BK, SB, an + BM * BK, tid);
                stage64x32(Vn + off, SB, bn, tid);
                stage64x32(Vn + off + BK, SB, bn + 64 * BK, tid);
                wait_vm6();
            } else {
                wait_vm0();
            }
            barrier_raw();
            mfma_step_pv_swz(as, bs, acc, lane, wave);
            mfma_step_pv_swz(as + BM * BK, bs + 64 * BK, acc, lane, wave);
            barrier_raw();
        }
#pragma unroll
        for (int mt = 0; mt < 2; mt++)
#pragma unroll
            for (int nt = 0; nt < 4; nt++)
#pragma unroll
                for (int r = 0; r < 4; r++) {
                    const size_t q = qm0 + wave * 32 + mt * 16 + quad * 4 + r;
                    const size_t n = n0 + nt * 16 + fr;
                    Ob[q * DD + n] = acc[mt][nt][r];
                }
    }
}

extern "C" void kernel_launch(void* const* d_in, const int* in_sizes, int n_in,
                              void* d_out, int out_size, void* d_ws, size_t ws_size,
                              hipStream_t stream)
{
    const float* x  = (const float*)d_in[0];
    const float* Wq = (const float*)d_in[1];
    const float* Wk = (const float*)d_in[2];
    const float* Wv = (const float*)d_in[3];
    float* out = (float*)d_out;

    // ws layout (~105 MB): [xb 16.8M][T 16.8M][Vt 16.8M][Sc 33.6M][Pp 16.8M]
    // [Wvt 2M][Mp 2M].  Mp4 (16.8 MB of fp32 mm partials) ALIASES the Sc
    // region: written by prep_mm, consumed by mm_reduce, then Sc overwrites
    // it in scores_mfma — all strictly ordered on the serial stream.
    const size_t XE = (size_t)NB * SB * DD;   // 8.39M elems
    const size_t WE = (size_t)DD * DD;        // 1.05M elems
    short* xb  = (short*)d_ws;
    short* T   = xb + XE;
    short* Vt  = T + XE;
    short* Sc  = Vt + XE;                     // NB*SB*SB shorts
    float* Pp  = (float*)(Sc + (size_t)NB * SB * SB);
    short* Wvt = (short*)(Pp + (size_t)NB * 1024 * DD);
    short* Mp  = Wvt + WE;
    float* Mp4 = (float*)Sc;                  // 4*WE fp32, dead before scores

    prep_mm<<<dim3(256 + 4096 + 256), 256, 0, stream>>>(
        x, Wq, Wk, Wv, xb, Wvt, Mp4);
    mm_reduce<<<dim3(1024), 256, 0, stream>>>(Mp4, Mp);
    tv_gemm<<<dim3(4, 32, 2), 512, 0, stream>>>(xb, Mp, Wvt, T, Vt);
    scores_mfma<<<dim3(272, NB), 256, 0, stream>>>(T, xb, Sc);
    softmax_kernel<<<dim3(NB * SB), 256, 0, stream>>>(Sc);
    pv_mfma<<<dim3(DD / 64, 8, NB), 256, 0, stream>>>(Sc, Vt, out);
}